// Round 9
// baseline (606.371 us; speedup 1.0000x reference)
//
#include <hip/hip_runtime.h>
#include <math.h>

#define N_NODES 131072
#define N_EDGES 524288
#define IN_DIM_ 78
#define HID_ 64
#define HEADS_ 4
#define NG 4096
#define NPG 32
#define NLAYERS 3
#define NEG_SLOPE 0.2f

typedef __attribute__((ext_vector_type(8))) short bf16x8;
typedef __attribute__((ext_vector_type(4))) float f32x4;

// bf16 helpers (round-to-nearest-even)
__device__ __forceinline__ unsigned short f2bf(float f) {
    unsigned int u = __float_as_uint(f);
    u = (u + 0x7FFF + ((u >> 16) & 1)) >> 16;
    return (unsigned short)u;
}
__device__ __forceinline__ float bf2f(unsigned short u) {
    return __uint_as_float(((unsigned int)u) << 16);
}

// ---------------- CSR build ----------------

__global__ void init_counts(int* __restrict__ cnt) {
    int n = blockIdx.x * blockDim.x + threadIdx.x;
    if (n < N_NODES) cnt[n] = 1;   // 1 = the self loop
}

__global__ void count_edges(const int* __restrict__ dst, int* __restrict__ cnt) {
    int e = blockIdx.x * blockDim.x + threadIdx.x;
    if (e < N_EDGES) atomicAdd(&cnt[dst[e]], 1);
}

__global__ void scan_kernel(const int* __restrict__ cnt, int* __restrict__ offsets) {
    __shared__ int sums[1024];
    const int t = threadIdx.x;
    const int CHUNK = N_NODES / 1024;  // 128
    int base = t * CHUNK;
    int s = 0;
    for (int j = 0; j < CHUNK / 4; ++j) {
        int4 v = ((const int4*)(cnt + base))[j];
        s += v.x + v.y + v.z + v.w;
    }
    sums[t] = s;
    __syncthreads();
    for (int off = 1; off < 1024; off <<= 1) {
        int v = (t >= off) ? sums[t - off] : 0;
        __syncthreads();
        sums[t] += v;
        __syncthreads();
    }
    int run = (t == 0) ? 0 : sums[t - 1];
    for (int j = 0; j < CHUNK / 4; ++j) {
        int4 c = ((const int4*)(cnt + base))[j];
        int4 o;
        o.x = run; run += c.x;
        o.y = run; run += c.y;
        o.z = run; run += c.z;
        o.w = run; run += c.w;
        ((int4*)(offsets + base))[j] = o;
    }
    if (t == 1023) offsets[N_NODES] = run;
}

__global__ void place_self(const int* __restrict__ offsets, int* __restrict__ cursor,
                           int* __restrict__ csr_src) {
    int n = blockIdx.x * blockDim.x + threadIdx.x;
    if (n < N_NODES) {
        int o = offsets[n];
        csr_src[o] = n;
        cursor[n] = o + 1;
    }
}

__global__ void scatter_edges(const int* __restrict__ src, const int* __restrict__ dst,
                              int* __restrict__ cursor, int* __restrict__ csr_src) {
    int e = blockIdx.x * blockDim.x + threadIdx.x;
    if (e < N_EDGES) {
        int d = dst[e];
        int pos = atomicAdd(&cursor[d], 1);
        csr_src[pos] = src[e];
    }
}

// ---------------- W split -> MFMA-fragment-major layout ----------------
// W [K][256] f32 -> WfH/WfL arranged so that the B-fragment for (ch, ct) is
// the 1KB block Wf[((ch*16+ct)*64 + lane)*8 .. +8] — one fully-coalesced
// bf16x8 load per lane. lane = lg*16+li; col = ct*16+li; k = ch*32+lg*8+j.
__global__ void wsplit_frag(const float* __restrict__ W, int K,
                            unsigned short* __restrict__ WfH, unsigned short* __restrict__ WfL) {
    int idx = blockIdx.x * 256 + threadIdx.x;   // 0..24575 over (k=96, col=256)
    int k = idx >> 8, col = idx & 255;
    float w = (k < K) ? W[k * 256 + col] : 0.f;
    unsigned short hi = f2bf(w);
    unsigned short lo = f2bf(w - bf2f(hi));
    int ch = k >> 5, kk = k & 31;
    int lg = kk >> 3, j = kk & 7;
    int ct = col >> 4, li = col & 15;
    size_t o = ((size_t)(ch * 16 + ct) * 64 + (lg * 16 + li)) * 8 + j;
    WfH[o] = hi;
    WfL[o] = lo;
}

// ---------------- MFMA GEMM: coalesced B (fragment-major) + LDS A ----------------
// Block: 256 threads = 4 waves. Tile: 64 rows x 256 cols.
// Wave w: rows (w>>1)*32..+31 (2 row-tiles), col-tiles (w&1)*8 + 0..7.
// A staged hi/lo to LDS with CONTIGUOUS global reads; fragments via
// ds_read_b128 (<=2-way bank aliasing). B fragments: one coalesced 1KB
// global load per (ch,ct) from L2-resident Wf. bf16x3: Ah*Bh+Al*Bh+Ah*Bl.
template<int NCH, int K>
__global__ __launch_bounds__(256)
void gemm_mfma(const float* __restrict__ A,
               const unsigned short* __restrict__ WfH,
               const unsigned short* __restrict__ WfL,
               const float* __restrict__ a_src, const float* __restrict__ a_dst,
               unsigned short* __restrict__ h, float* __restrict__ als, float* __restrict__ ald) {
    constexpr int KP = NCH * 32;
    constexpr int ST = (KP == 96) ? 104 : 72;   // ushort row stride
    __shared__ __align__(16) unsigned short AsH[64 * ST];
    __shared__ __align__(16) unsigned short AsL[64 * ST];
    const int tid = threadIdx.x;
    const int w = tid >> 6;
    const int lane = tid & 63;
    const int li = lane & 15, lg = lane >> 4;
    const int row0 = blockIdx.x * 64;
    const int r0 = (w >> 1) * 32;
    const int c0t = (w & 1) * 8;                // col-tile base

    // ---- stage A hi/lo into LDS (contiguous global reads) ----
    {
        const float* Ab = A + (size_t)row0 * K;
        for (int i = tid; i < 64 * K; i += 256) {
            int row = i / K, k = i - row * K;
            float v = Ab[i];
            unsigned short hi = f2bf(v);
            unsigned short lo = f2bf(v - bf2f(hi));
            AsH[row * ST + k] = hi;
            AsL[row * ST + k] = lo;
        }
        if constexpr (KP > K) {
            constexpr int PAD = KP - K;
            for (int i = tid; i < 64 * PAD; i += 256) {
                int row = i / PAD, k = K + (i - row * PAD);
                AsH[row * ST + k] = 0;
                AsL[row * ST + k] = 0;
            }
        }
    }
    __syncthreads();

    f32x4 acc[2][8];
    #pragma unroll
    for (int rt = 0; rt < 2; ++rt)
        #pragma unroll
        for (int ct = 0; ct < 8; ++ct)
            acc[rt][ct] = (f32x4){0.f, 0.f, 0.f, 0.f};

    #pragma unroll
    for (int ch = 0; ch < NCH; ++ch) {
        const int kb = ch * 32 + lg * 8;
        bf16x8 ah0 = *(const bf16x8*)&AsH[(r0 + li) * ST + kb];
        bf16x8 ah1 = *(const bf16x8*)&AsH[(r0 + 16 + li) * ST + kb];
        bf16x8 al0 = *(const bf16x8*)&AsL[(r0 + li) * ST + kb];
        bf16x8 al1 = *(const bf16x8*)&AsL[(r0 + 16 + li) * ST + kb];
        #pragma unroll
        for (int ct = 0; ct < 8; ++ct) {
            const size_t fo = (((size_t)ch * 16 + c0t + ct) * 64 + lane) * 8;
            bf16x8 bh = *(const bf16x8*)&WfH[fo];
            bf16x8 bl = *(const bf16x8*)&WfL[fo];
            acc[0][ct] = __builtin_amdgcn_mfma_f32_16x16x32_bf16(ah0, bh, acc[0][ct], 0, 0, 0);
            acc[1][ct] = __builtin_amdgcn_mfma_f32_16x16x32_bf16(ah1, bh, acc[1][ct], 0, 0, 0);
            acc[0][ct] = __builtin_amdgcn_mfma_f32_16x16x32_bf16(al0, bh, acc[0][ct], 0, 0, 0);
            acc[1][ct] = __builtin_amdgcn_mfma_f32_16x16x32_bf16(al1, bh, acc[1][ct], 0, 0, 0);
            acc[0][ct] = __builtin_amdgcn_mfma_f32_16x16x32_bf16(ah0, bl, acc[0][ct], 0, 0, 0);
            acc[1][ct] = __builtin_amdgcn_mfma_f32_16x16x32_bf16(ah1, bl, acc[1][ct], 0, 0, 0);
        }
    }

    // ---- epilogue: h (bf16) via lane-paired u32 stores + fused alpha dots ----
    // D layout per tile: col = li, row = lg*4 + reg (validated r7/r8).
    #pragma unroll
    for (int rt = 0; rt < 2; ++rt) {
        #pragma unroll
        for (int ct = 0; ct < 8; ++ct) {
            #pragma unroll
            for (int reg = 0; reg < 4; ++reg) {
                int row = row0 + r0 + rt * 16 + lg * 4 + reg;
                int col = (c0t + ct) * 16 + li;
                unsigned int v = f2bf(acc[rt][ct][reg]);
                unsigned int pv = (unsigned int)__shfl_xor((int)v, 1, 64) & 0xFFFFu;
                if ((li & 1) == 0)
                    *(unsigned int*)&h[(size_t)row * 256 + col] = v | (pv << 16);
            }
        }
    }

    float as_v[8], ad_v[8];
    #pragma unroll
    for (int ct = 0; ct < 8; ++ct) {
        int ghead = (w & 1) * 2 + (ct >> 2);
        as_v[ct] = a_src[ghead * 64 + (ct & 3) * 16 + li];
        ad_v[ct] = a_dst[ghead * 64 + (ct & 3) * 16 + li];
    }
    #pragma unroll
    for (int rt = 0; rt < 2; ++rt) {
        #pragma unroll
        for (int hl = 0; hl < 2; ++hl) {
            #pragma unroll
            for (int reg = 0; reg < 4; ++reg) {
                float ps = 0.f, pd = 0.f;
                #pragma unroll
                for (int c4 = 0; c4 < 4; ++c4) {
                    int ct = hl * 4 + c4;
                    ps += acc[rt][ct][reg] * as_v[ct];
                    pd += acc[rt][ct][reg] * ad_v[ct];
                }
                ps += __shfl_xor(ps, 1, 64); ps += __shfl_xor(ps, 2, 64);
                ps += __shfl_xor(ps, 4, 64); ps += __shfl_xor(ps, 8, 64);
                pd += __shfl_xor(pd, 1, 64); pd += __shfl_xor(pd, 2, 64);
                pd += __shfl_xor(pd, 4, 64); pd += __shfl_xor(pd, 8, 64);
                if (li == 0) {
                    int row = row0 + r0 + rt * 16 + lg * 4 + reg;
                    int ghead = (w & 1) * 2 + hl;
                    als[row * 4 + ghead] = ps;
                    ald[row * 4 + ghead] = pd;
                }
            }
        }
    }
}

// ---------------- per-node softmax-weighted aggregation ----------------
__device__ __forceinline__ float pick4(float4 v, int idx) {
    float r = v.x;
    r = (idx == 1) ? v.y : r;
    r = (idx == 2) ? v.z : r;
    r = (idx == 3) ? v.w : r;
    return r;
}

__global__ __launch_bounds__(256)
void aggregate(const int* __restrict__ offsets, const int* __restrict__ csr_src,
               const unsigned short* __restrict__ h, const float* __restrict__ als,
               const float* __restrict__ ald, const float* __restrict__ bias,
               float* __restrict__ hout) {
    const int lane = threadIdx.x & 63;
    const int wid = __builtin_amdgcn_readfirstlane(threadIdx.x >> 6);
    const int n = blockIdx.x * 4 + wid;
    const int head = lane >> 4;
    const int d4 = (lane & 15) * 4;

    const int o0 = __builtin_amdgcn_readfirstlane(offsets[n]);
    const int o1 = __builtin_amdgcn_readfirstlane(offsets[n + 1]);

    const float ad_h = pick4(*(const float4*)&ald[n * 4], head);

    float4 acc = make_float4(0.f, 0.f, 0.f, 0.f);
    float den = 0.f;

    int i = o0;
    for (; i + 4 <= o1; i += 4) {
        int s0 = __builtin_amdgcn_readfirstlane(csr_src[i + 0]);
        int s1 = __builtin_amdgcn_readfirstlane(csr_src[i + 1]);
        int s2 = __builtin_amdgcn_readfirstlane(csr_src[i + 2]);
        int s3 = __builtin_amdgcn_readfirstlane(csr_src[i + 3]);
        float4 as0 = *(const float4*)&als[s0 * 4];
        float4 as1 = *(const float4*)&als[s1 * 4];
        float4 as2 = *(const float4*)&als[s2 * 4];
        float4 as3 = *(const float4*)&als[s3 * 4];
        ushort4 u0 = ((const ushort4*)(h + (size_t)s0 * 256))[lane];
        ushort4 u1 = ((const ushort4*)(h + (size_t)s1 * 256))[lane];
        ushort4 u2 = ((const ushort4*)(h + (size_t)s2 * 256))[lane];
        ushort4 u3 = ((const ushort4*)(h + (size_t)s3 * 256))[lane];
        float e0 = pick4(as0, head) + ad_h; e0 = e0 > 0.f ? e0 : NEG_SLOPE * e0;
        float e1 = pick4(as1, head) + ad_h; e1 = e1 > 0.f ? e1 : NEG_SLOPE * e1;
        float e2 = pick4(as2, head) + ad_h; e2 = e2 > 0.f ? e2 : NEG_SLOPE * e2;
        float e3 = pick4(as3, head) + ad_h; e3 = e3 > 0.f ? e3 : NEG_SLOPE * e3;
        float p0 = __expf(e0), p1 = __expf(e1), p2 = __expf(e2), p3 = __expf(e3);
        den += p0 + p1 + p2 + p3;
        acc.x += p0 * bf2f(u0.x) + p1 * bf2f(u1.x) + p2 * bf2f(u2.x) + p3 * bf2f(u3.x);
        acc.y += p0 * bf2f(u0.y) + p1 * bf2f(u1.y) + p2 * bf2f(u2.y) + p3 * bf2f(u3.y);
        acc.z += p0 * bf2f(u0.z) + p1 * bf2f(u1.z) + p2 * bf2f(u2.z) + p3 * bf2f(u3.z);
        acc.w += p0 * bf2f(u0.w) + p1 * bf2f(u1.w) + p2 * bf2f(u2.w) + p3 * bf2f(u3.w);
    }
    for (; i < o1; ++i) {
        int s = __builtin_amdgcn_readfirstlane(csr_src[i]);
        float4 asv = *(const float4*)&als[s * 4];
        ushort4 uv = ((const ushort4*)(h + (size_t)s * 256))[lane];
        float e = pick4(asv, head) + ad_h;
        e = e > 0.f ? e : NEG_SLOPE * e;
        float p = __expf(e);
        den += p;
        acc.x += p * bf2f(uv.x); acc.y += p * bf2f(uv.y);
        acc.z += p * bf2f(uv.z); acc.w += p * bf2f(uv.w);
    }

    const float rden = 1.f / den;
    float c0 = acc.x * rden, c1 = acc.y * rden, c2 = acc.z * rden, c3 = acc.w * rden;
    c0 += __shfl_xor(c0, 16, 64); c0 += __shfl_xor(c0, 32, 64);
    c1 += __shfl_xor(c1, 16, 64); c1 += __shfl_xor(c1, 32, 64);
    c2 += __shfl_xor(c2, 16, 64); c2 += __shfl_xor(c2, 32, 64);
    c3 += __shfl_xor(c3, 16, 64); c3 += __shfl_xor(c3, 32, 64);

    if (lane < 16) {
        float4 bv = *(const float4*)&bias[d4];
        float v0 = 0.25f * c0 + bv.x;
        float v1 = 0.25f * c1 + bv.y;
        float v2 = 0.25f * c2 + bv.z;
        float v3 = 0.25f * c3 + bv.w;
        float4 o;
        o.x = v0 > 0.f ? v0 : 0.f;
        o.y = v1 > 0.f ? v1 : 0.f;
        o.z = v2 > 0.f ? v2 : 0.f;
        o.w = v3 > 0.f ? v3 : 0.f;
        *(float4*)&hout[(size_t)n * 64 + d4] = o;
    }
}

// ---------------- per-graph pooling ----------------
__global__ __launch_bounds__(256)
void pool_kernel(const float* __restrict__ hout, float* __restrict__ pooled, int layer) {
    const int wid = threadIdx.x >> 6, lane = threadIdx.x & 63;
    const int g = blockIdx.x * 4 + wid;
    float s = 0.f;
    const float* p = &hout[(size_t)g * NPG * 64 + lane];
    #pragma unroll 8
    for (int i = 0; i < NPG; ++i) s += p[i * 64];
    pooled[(g * NLAYERS + layer) * 64 + lane] = s;
}

// ---------------- final layer-attention ----------------
__global__ __launch_bounds__(256)
void final_kernel(const float* __restrict__ pooled, const float* __restrict__ pw,
                  const float* __restrict__ pb, float* __restrict__ out) {
    const int wid = threadIdx.x >> 6, lane = threadIdx.x & 63;
    const int g = blockIdx.x * 4 + wid;
    float v0 = pooled[(g * 3 + 0) * 64 + lane];
    float v1 = pooled[(g * 3 + 1) * 64 + lane];
    float v2 = pooled[(g * 3 + 2) * 64 + lane];
    float w = pw[lane];
    float l0 = v0 * w, l1 = v1 * w, l2 = v2 * w;
    #pragma unroll
    for (int m = 1; m < 64; m <<= 1) {
        l0 += __shfl_xor(l0, m, 64);
        l1 += __shfl_xor(l1, m, 64);
        l2 += __shfl_xor(l2, m, 64);
    }
    float bb = pb[0];
    l0 += bb; l1 += bb; l2 += bb;
    float mx = fmaxf(l0, fmaxf(l1, l2));
    float e0 = __expf(l0 - mx), e1 = __expf(l1 - mx), e2 = __expf(l2 - mx);
    float inv = 1.f / (e0 + e1 + e2);
    out[(size_t)g * 64 + lane] = (v0 * e0 + v1 * e1 + v2 * e2) * inv;
}

// ---------------- launch ----------------
extern "C" void kernel_launch(void* const* d_in, const int* in_sizes, int n_in,
                              void* d_out, int out_size, void* d_ws, size_t ws_size,
                              hipStream_t stream) {
    const float* x  = (const float*)d_in[0];
    const int*   ei = (const int*)d_in[1];
    const float* W[3]    = {(const float*)d_in[3], (const float*)d_in[7],  (const float*)d_in[11]};
    const float* asrc[3] = {(const float*)d_in[4], (const float*)d_in[8],  (const float*)d_in[12]};
    const float* adst[3] = {(const float*)d_in[5], (const float*)d_in[9],  (const float*)d_in[13]};
    const float* bias[3] = {(const float*)d_in[6], (const float*)d_in[10], (const float*)d_in[14]};
    const float* pw = (const float*)d_in[15];
    const float* pb = (const float*)d_in[16];
    float* out = (float*)d_out;

    char* ws = (char*)d_ws;
    size_t off = 0;
    auto alloc = [&](size_t bytes) -> void* {
        void* p = ws + off;
        off = (off + bytes + 255) & ~(size_t)255;
        return p;
    };
    int*   offsets = (int*)alloc((N_NODES + 1) * 4);
    int*   cursor  = (int*)alloc(N_NODES * 4);
    int*   csr_src = (int*)alloc((size_t)(N_EDGES + N_NODES) * 4);
    unsigned short* h = (unsigned short*)alloc((size_t)N_NODES * 256 * 2);  // 67 MB bf16
    float* als     = (float*)alloc((size_t)N_NODES * 4 * 4);
    float* ald     = (float*)alloc((size_t)N_NODES * 4 * 4);
    float* hbuf0   = (float*)alloc((size_t)N_NODES * 64 * 4);
    float* hbuf1   = (float*)alloc((size_t)N_NODES * 64 * 4);
    float* pooled  = (float*)alloc((size_t)NG * 3 * 64 * 4);
    unsigned short* WfH = (unsigned short*)alloc((size_t)96 * 256 * 2);
    unsigned short* WfL = (unsigned short*)alloc((size_t)96 * 256 * 2);
    (void)ws_size; (void)in_sizes; (void)n_in; (void)out_size;

    const int* srcp = ei;
    const int* dstp = ei + N_EDGES;

    init_counts<<<N_NODES / 256, 256, 0, stream>>>(cursor);
    count_edges<<<N_EDGES / 256, 256, 0, stream>>>(dstp, cursor);
    scan_kernel<<<1, 1024, 0, stream>>>(cursor, offsets);
    place_self<<<N_NODES / 256, 256, 0, stream>>>(offsets, cursor, csr_src);
    scatter_edges<<<N_EDGES / 256, 256, 0, stream>>>(srcp, dstp, cursor, csr_src);

    const float* in = x;
    for (int l = 0; l < 3; ++l) {
        const int K = (l == 0) ? IN_DIM_ : HID_;
        wsplit_frag<<<96, 256, 0, stream>>>(W[l], K, WfH, WfL);
        if (l == 0)
            gemm_mfma<3, IN_DIM_><<<N_NODES / 64, 256, 0, stream>>>(in, WfH, WfL, asrc[l], adst[l], h, als, ald);
        else
            gemm_mfma<2, HID_><<<N_NODES / 64, 256, 0, stream>>>(in, WfH, WfL, asrc[l], adst[l], h, als, ald);
        float* ho = (l & 1) ? hbuf1 : hbuf0;
        aggregate<<<N_NODES / 4, 256, 0, stream>>>(offsets, csr_src, h, als, ald, bias[l], ho);
        pool_kernel<<<NG / 4, 256, 0, stream>>>(ho, pooled, l);
        in = ho;
    }
    final_kernel<<<NG / 4, 256, 0, stream>>>(pooled, pw, pb, out);
}

// Round 10
// 535.248 us; speedup vs baseline: 1.1329x; 1.1329x over previous
//
#include <hip/hip_runtime.h>
#include <math.h>

#define N_NODES 131072
#define N_EDGES 524288
#define IN_DIM_ 78
#define HID_ 64
#define HEADS_ 4
#define NG 4096
#define NPG 32
#define NLAYERS 3
#define NEG_SLOPE 0.2f

typedef __attribute__((ext_vector_type(8))) short bf16x8;
typedef __attribute__((ext_vector_type(4))) float f32x4;

// bf16 helpers (round-to-nearest-even)
__device__ __forceinline__ unsigned short f2bf(float f) {
    unsigned int u = __float_as_uint(f);
    u = (u + 0x7FFF + ((u >> 16) & 1)) >> 16;
    return (unsigned short)u;
}
__device__ __forceinline__ float bf2f(unsigned short u) {
    return __uint_as_float(((unsigned int)u) << 16);
}

// ---------------- CSR build ----------------

__global__ void init_counts(int* __restrict__ cnt) {
    int n = blockIdx.x * blockDim.x + threadIdx.x;
    if (n < N_NODES) cnt[n] = 1;   // 1 = the self loop
}

__global__ void count_edges(const int* __restrict__ dst, int* __restrict__ cnt) {
    int e = blockIdx.x * blockDim.x + threadIdx.x;
    if (e < N_EDGES) atomicAdd(&cnt[dst[e]], 1);
}

__global__ void scan_kernel(const int* __restrict__ cnt, int* __restrict__ offsets) {
    __shared__ int sums[1024];
    const int t = threadIdx.x;
    const int CHUNK = N_NODES / 1024;  // 128
    int base = t * CHUNK;
    int s = 0;
    for (int j = 0; j < CHUNK / 4; ++j) {
        int4 v = ((const int4*)(cnt + base))[j];
        s += v.x + v.y + v.z + v.w;
    }
    sums[t] = s;
    __syncthreads();
    for (int off = 1; off < 1024; off <<= 1) {
        int v = (t >= off) ? sums[t - off] : 0;
        __syncthreads();
        sums[t] += v;
        __syncthreads();
    }
    int run = (t == 0) ? 0 : sums[t - 1];
    for (int j = 0; j < CHUNK / 4; ++j) {
        int4 c = ((const int4*)(cnt + base))[j];
        int4 o;
        o.x = run; run += c.x;
        o.y = run; run += c.y;
        o.z = run; run += c.z;
        o.w = run; run += c.w;
        ((int4*)(offsets + base))[j] = o;
    }
    if (t == 1023) offsets[N_NODES] = run;
}

__global__ void place_self(const int* __restrict__ offsets, int* __restrict__ cursor,
                           int* __restrict__ csr_src) {
    int n = blockIdx.x * blockDim.x + threadIdx.x;
    if (n < N_NODES) {
        int o = offsets[n];
        csr_src[o] = n;
        cursor[n] = o + 1;
    }
}

__global__ void scatter_edges(const int* __restrict__ src, const int* __restrict__ dst,
                              int* __restrict__ cursor, int* __restrict__ csr_src) {
    int e = blockIdx.x * blockDim.x + threadIdx.x;
    if (e < N_EDGES) {
        int d = dst[e];
        int pos = atomicAdd(&cursor[d], 1);
        csr_src[pos] = src[e];
    }
}

// ---------------- W split -> MFMA-fragment-major layout (18 tiles/chunk) ----------------
// Tile t<16: h columns (col = t*16+li). Tiles 16/17: augmented alpha columns
// (W·a_src / W·a_dst per head in li<4, zeros elsewhere), written by waug.
// Fragment for (ch,t) = 1KB block Wf[((ch*18+t)*64 + lane)*8 .. +8].
__global__ void wsplit_frag(const float* __restrict__ W, int K,
                            unsigned short* __restrict__ WfH, unsigned short* __restrict__ WfL) {
    int idx = blockIdx.x * 256 + threadIdx.x;   // 96*256 over (k, col)
    int k = idx >> 8, col = idx & 255;
    float w = (k < K) ? W[k * 256 + col] : 0.f;
    unsigned short hi = f2bf(w);
    unsigned short lo = f2bf(w - bf2f(hi));
    int ch = k >> 5, kk = k & 31;
    int lg = kk >> 3, j = kk & 7;
    int ct = col >> 4, li = col & 15;
    size_t o = (((size_t)ch * 18 + ct) * 64 + (lg * 16 + li)) * 8 + j;
    WfH[o] = hi;
    WfL[o] = lo;
}

// aug columns: aug[k][hd] = sum_d W[k][hd*64+d] * a[hd][d]  (f32, exact-ish)
__global__ void waug(const float* __restrict__ W, const float* __restrict__ asrc,
                     const float* __restrict__ adst, int K,
                     unsigned short* __restrict__ WfH, unsigned short* __restrict__ WfL) {
    int k = blockIdx.x;          // 0..95
    int t = threadIdx.x;         // 0..31
    int tile = 16 + (t >> 4), li = t & 15;
    float v = 0.f;
    if (li < 4 && k < K) {
        const float* a = (tile == 16) ? asrc : adst;
        const float* wr = W + k * 256 + li * 64;
        #pragma unroll 8
        for (int d = 0; d < 64; ++d) v += wr[d] * a[li * 64 + d];
    }
    unsigned short hi = f2bf(v);
    unsigned short lo = f2bf(v - bf2f(hi));
    int ch = k >> 5, kk = k & 31;
    int lg = kk >> 3, j = kk & 7;
    size_t o = (((size_t)ch * 18 + tile) * 64 + (lg * 16 + li)) * 8 + j;
    WfH[o] = hi;
    WfL[o] = lo;
}

// ---------------- MFMA GEMM: zero-shuffle epilogue, alphas as MFMA columns ----------------
// Block: 256 threads = 4 waves. Tile: 64 rows x 256(+8 aug) cols.
// Wave w: rows (w>>1)*32..+31, h-tiles (w&1)*8..+7, plus aug tile 16+(w&1)
// (als for even col-waves, ald for odd). A fragments straight from global,
// split hi/lo in registers (r8-proven). B fragments: coalesced 1KB loads from
// fragment-major Wf (L2-resident). bf16x3: Ah*Bh + Al*Bh + Ah*Bl.
// Epilogue: direct ushort h-stores + direct f32 alpha stores — NO shuffles.
template<int NCH, int K>
__global__ __launch_bounds__(256)
void gemm_mfma(const float* __restrict__ A,
               const unsigned short* __restrict__ WfH,
               const unsigned short* __restrict__ WfL,
               unsigned short* __restrict__ h, float* __restrict__ als, float* __restrict__ ald) {
    const int tid = threadIdx.x;
    const int w = tid >> 6;
    const int lane = tid & 63;
    const int li = lane & 15, lg = lane >> 4;
    const int row0 = blockIdx.x * 64;
    const int r0 = (w >> 1) * 32;
    const int cw = w & 1;

    // ---- A fragments: global -> registers, split hi/lo ----
    bf16x8 ah[NCH][2], al[NCH][2];
    #pragma unroll
    for (int ch = 0; ch < NCH; ++ch) {
        #pragma unroll
        for (int rt = 0; rt < 2; ++rt) {
            const int row = row0 + r0 + rt * 16 + li;
            const int kb = ch * 32 + lg * 8;
            float t[8];
            if ((ch + 1) * 32 <= K) {
                if constexpr ((K % 4) == 0) {
                    const float4* ap = (const float4*)(A + (size_t)row * K + kb);
                    float4 v0 = ap[0], v1 = ap[1];
                    t[0] = v0.x; t[1] = v0.y; t[2] = v0.z; t[3] = v0.w;
                    t[4] = v1.x; t[5] = v1.y; t[6] = v1.z; t[7] = v1.w;
                } else {
                    const float2* ap = (const float2*)(A + (size_t)row * K + kb);
                    #pragma unroll
                    for (int j = 0; j < 4; ++j) {
                        float2 v = ap[j];
                        t[2 * j] = v.x; t[2 * j + 1] = v.y;
                    }
                }
            } else {
                const float2* ap = (const float2*)(A + (size_t)row * K + kb);
                #pragma unroll
                for (int j = 0; j < 4; ++j) {   // K even -> pairs never straddle
                    float2 v = (kb + 2 * j + 1 < K) ? ap[j] : make_float2(0.f, 0.f);
                    t[2 * j] = v.x; t[2 * j + 1] = v.y;
                }
            }
            bf16x8 hh, ll;
            #pragma unroll
            for (int j = 0; j < 8; ++j) {
                unsigned short hi = f2bf(t[j]);
                unsigned short lo = f2bf(t[j] - bf2f(hi));
                hh[j] = (short)hi; ll[j] = (short)lo;
            }
            ah[ch][rt] = hh; al[ch][rt] = ll;
        }
    }

    f32x4 acc[2][9];
    #pragma unroll
    for (int rt = 0; rt < 2; ++rt)
        #pragma unroll
        for (int ci = 0; ci < 9; ++ci)
            acc[rt][ci] = (f32x4){0.f, 0.f, 0.f, 0.f};

    // ---- main loop: coalesced B fragment loads + 6 MFMA per (ch, tile) ----
    #pragma unroll
    for (int ch = 0; ch < NCH; ++ch) {
        #pragma unroll
        for (int ci = 0; ci < 9; ++ci) {
            const int t = (ci < 8) ? (cw * 8 + ci) : (16 + cw);
            const size_t fo = (((size_t)ch * 18 + t) * 64 + lane) * 8;
            bf16x8 bh = *(const bf16x8*)&WfH[fo];
            bf16x8 bl = *(const bf16x8*)&WfL[fo];
            acc[0][ci] = __builtin_amdgcn_mfma_f32_16x16x32_bf16(ah[ch][0], bh, acc[0][ci], 0, 0, 0);
            acc[1][ci] = __builtin_amdgcn_mfma_f32_16x16x32_bf16(ah[ch][1], bh, acc[1][ci], 0, 0, 0);
            acc[0][ci] = __builtin_amdgcn_mfma_f32_16x16x32_bf16(al[ch][0], bh, acc[0][ci], 0, 0, 0);
            acc[1][ci] = __builtin_amdgcn_mfma_f32_16x16x32_bf16(al[ch][1], bh, acc[1][ci], 0, 0, 0);
            acc[0][ci] = __builtin_amdgcn_mfma_f32_16x16x32_bf16(ah[ch][0], bl, acc[0][ci], 0, 0, 0);
            acc[1][ci] = __builtin_amdgcn_mfma_f32_16x16x32_bf16(ah[ch][1], bl, acc[1][ci], 0, 0, 0);
        }
    }

    // ---- epilogue (zero shuffles) ----
    // D layout per tile: col = li, row = lg*4 + reg (validated r7/r8).
    #pragma unroll
    for (int rt = 0; rt < 2; ++rt) {
        #pragma unroll
        for (int ci = 0; ci < 8; ++ci) {
            #pragma unroll
            for (int reg = 0; reg < 4; ++reg) {
                int row = row0 + r0 + rt * 16 + lg * 4 + reg;
                int col = cw * 128 + ci * 16 + li;
                h[(size_t)row * 256 + col] = f2bf(acc[rt][ci][reg]);
            }
        }
    }
    float* __restrict__ tgt = cw ? ald : als;
    #pragma unroll
    for (int rt = 0; rt < 2; ++rt) {
        #pragma unroll
        for (int reg = 0; reg < 4; ++reg) {
            int row = row0 + r0 + rt * 16 + lg * 4 + reg;
            if (li < 4) tgt[row * 4 + li] = acc[rt][8][reg];
        }
    }
}

// ---------------- per-node softmax-weighted aggregation ----------------
__device__ __forceinline__ float pick4(float4 v, int idx) {
    float r = v.x;
    r = (idx == 1) ? v.y : r;
    r = (idx == 2) ? v.z : r;
    r = (idx == 3) ? v.w : r;
    return r;
}

__global__ __launch_bounds__(256)
void aggregate(const int* __restrict__ offsets, const int* __restrict__ csr_src,
               const unsigned short* __restrict__ h, const float* __restrict__ als,
               const float* __restrict__ ald, const float* __restrict__ bias,
               float* __restrict__ hout) {
    const int lane = threadIdx.x & 63;
    const int wid = __builtin_amdgcn_readfirstlane(threadIdx.x >> 6);
    const int n = blockIdx.x * 4 + wid;
    const int head = lane >> 4;
    const int d4 = (lane & 15) * 4;

    const int o0 = __builtin_amdgcn_readfirstlane(offsets[n]);
    const int o1 = __builtin_amdgcn_readfirstlane(offsets[n + 1]);

    const float ad_h = pick4(*(const float4*)&ald[n * 4], head);

    float4 acc = make_float4(0.f, 0.f, 0.f, 0.f);
    float den = 0.f;

    int i = o0;
    for (; i + 4 <= o1; i += 4) {
        int s0 = __builtin_amdgcn_readfirstlane(csr_src[i + 0]);
        int s1 = __builtin_amdgcn_readfirstlane(csr_src[i + 1]);
        int s2 = __builtin_amdgcn_readfirstlane(csr_src[i + 2]);
        int s3 = __builtin_amdgcn_readfirstlane(csr_src[i + 3]);
        float4 as0 = *(const float4*)&als[s0 * 4];
        float4 as1 = *(const float4*)&als[s1 * 4];
        float4 as2 = *(const float4*)&als[s2 * 4];
        float4 as3 = *(const float4*)&als[s3 * 4];
        ushort4 u0 = ((const ushort4*)(h + (size_t)s0 * 256))[lane];
        ushort4 u1 = ((const ushort4*)(h + (size_t)s1 * 256))[lane];
        ushort4 u2 = ((const ushort4*)(h + (size_t)s2 * 256))[lane];
        ushort4 u3 = ((const ushort4*)(h + (size_t)s3 * 256))[lane];
        float e0 = pick4(as0, head) + ad_h; e0 = e0 > 0.f ? e0 : NEG_SLOPE * e0;
        float e1 = pick4(as1, head) + ad_h; e1 = e1 > 0.f ? e1 : NEG_SLOPE * e1;
        float e2 = pick4(as2, head) + ad_h; e2 = e2 > 0.f ? e2 : NEG_SLOPE * e2;
        float e3 = pick4(as3, head) + ad_h; e3 = e3 > 0.f ? e3 : NEG_SLOPE * e3;
        float p0 = __expf(e0), p1 = __expf(e1), p2 = __expf(e2), p3 = __expf(e3);
        den += p0 + p1 + p2 + p3;
        acc.x += p0 * bf2f(u0.x) + p1 * bf2f(u1.x) + p2 * bf2f(u2.x) + p3 * bf2f(u3.x);
        acc.y += p0 * bf2f(u0.y) + p1 * bf2f(u1.y) + p2 * bf2f(u2.y) + p3 * bf2f(u3.y);
        acc.z += p0 * bf2f(u0.z) + p1 * bf2f(u1.z) + p2 * bf2f(u2.z) + p3 * bf2f(u3.z);
        acc.w += p0 * bf2f(u0.w) + p1 * bf2f(u1.w) + p2 * bf2f(u2.w) + p3 * bf2f(u3.w);
    }
    for (; i < o1; ++i) {
        int s = __builtin_amdgcn_readfirstlane(csr_src[i]);
        float4 asv = *(const float4*)&als[s * 4];
        ushort4 uv = ((const ushort4*)(h + (size_t)s * 256))[lane];
        float e = pick4(asv, head) + ad_h;
        e = e > 0.f ? e : NEG_SLOPE * e;
        float p = __expf(e);
        den += p;
        acc.x += p * bf2f(uv.x); acc.y += p * bf2f(uv.y);
        acc.z += p * bf2f(uv.z); acc.w += p * bf2f(uv.w);
    }

    const float rden = 1.f / den;
    float c0 = acc.x * rden, c1 = acc.y * rden, c2 = acc.z * rden, c3 = acc.w * rden;
    c0 += __shfl_xor(c0, 16, 64); c0 += __shfl_xor(c0, 32, 64);
    c1 += __shfl_xor(c1, 16, 64); c1 += __shfl_xor(c1, 32, 64);
    c2 += __shfl_xor(c2, 16, 64); c2 += __shfl_xor(c2, 32, 64);
    c3 += __shfl_xor(c3, 16, 64); c3 += __shfl_xor(c3, 32, 64);

    if (lane < 16) {
        float4 bv = *(const float4*)&bias[d4];
        float v0 = 0.25f * c0 + bv.x;
        float v1 = 0.25f * c1 + bv.y;
        float v2 = 0.25f * c2 + bv.z;
        float v3 = 0.25f * c3 + bv.w;
        float4 o;
        o.x = v0 > 0.f ? v0 : 0.f;
        o.y = v1 > 0.f ? v1 : 0.f;
        o.z = v2 > 0.f ? v2 : 0.f;
        o.w = v3 > 0.f ? v3 : 0.f;
        *(float4*)&hout[(size_t)n * 64 + d4] = o;
    }
}

// ---------------- per-graph pooling ----------------
__global__ __launch_bounds__(256)
void pool_kernel(const float* __restrict__ hout, float* __restrict__ pooled, int layer) {
    const int wid = threadIdx.x >> 6, lane = threadIdx.x & 63;
    const int g = blockIdx.x * 4 + wid;
    float s = 0.f;
    const float* p = &hout[(size_t)g * NPG * 64 + lane];
    #pragma unroll 8
    for (int i = 0; i < NPG; ++i) s += p[i * 64];
    pooled[(g * NLAYERS + layer) * 64 + lane] = s;
}

// ---------------- final layer-attention ----------------
__global__ __launch_bounds__(256)
void final_kernel(const float* __restrict__ pooled, const float* __restrict__ pw,
                  const float* __restrict__ pb, float* __restrict__ out) {
    const int wid = threadIdx.x >> 6, lane = threadIdx.x & 63;
    const int g = blockIdx.x * 4 + wid;
    float v0 = pooled[(g * 3 + 0) * 64 + lane];
    float v1 = pooled[(g * 3 + 1) * 64 + lane];
    float v2 = pooled[(g * 3 + 2) * 64 + lane];
    float w = pw[lane];
    float l0 = v0 * w, l1 = v1 * w, l2 = v2 * w;
    #pragma unroll
    for (int m = 1; m < 64; m <<= 1) {
        l0 += __shfl_xor(l0, m, 64);
        l1 += __shfl_xor(l1, m, 64);
        l2 += __shfl_xor(l2, m, 64);
    }
    float bb = pb[0];
    l0 += bb; l1 += bb; l2 += bb;
    float mx = fmaxf(l0, fmaxf(l1, l2));
    float e0 = __expf(l0 - mx), e1 = __expf(l1 - mx), e2 = __expf(l2 - mx);
    float inv = 1.f / (e0 + e1 + e2);
    out[(size_t)g * 64 + lane] = (v0 * e0 + v1 * e1 + v2 * e2) * inv;
}

// ---------------- launch ----------------
extern "C" void kernel_launch(void* const* d_in, const int* in_sizes, int n_in,
                              void* d_out, int out_size, void* d_ws, size_t ws_size,
                              hipStream_t stream) {
    const float* x  = (const float*)d_in[0];
    const int*   ei = (const int*)d_in[1];
    const float* W[3]    = {(const float*)d_in[3], (const float*)d_in[7],  (const float*)d_in[11]};
    const float* asrc[3] = {(const float*)d_in[4], (const float*)d_in[8],  (const float*)d_in[12]};
    const float* adst[3] = {(const float*)d_in[5], (const float*)d_in[9],  (const float*)d_in[13]};
    const float* bias[3] = {(const float*)d_in[6], (const float*)d_in[10], (const float*)d_in[14]};
    const float* pw = (const float*)d_in[15];
    const float* pb = (const float*)d_in[16];
    float* out = (float*)d_out;

    char* ws = (char*)d_ws;
    size_t off = 0;
    auto alloc = [&](size_t bytes) -> void* {
        void* p = ws + off;
        off = (off + bytes + 255) & ~(size_t)255;
        return p;
    };
    int*   offsets = (int*)alloc((N_NODES + 1) * 4);
    int*   cursor  = (int*)alloc(N_NODES * 4);
    int*   csr_src = (int*)alloc((size_t)(N_EDGES + N_NODES) * 4);
    unsigned short* h = (unsigned short*)alloc((size_t)N_NODES * 256 * 2);  // 67 MB bf16
    float* als     = (float*)alloc((size_t)N_NODES * 4 * 4);
    float* ald     = (float*)alloc((size_t)N_NODES * 4 * 4);
    float* hbuf0   = (float*)alloc((size_t)N_NODES * 64 * 4);
    float* hbuf1   = (float*)alloc((size_t)N_NODES * 64 * 4);
    float* pooled  = (float*)alloc((size_t)NG * 3 * 64 * 4);
    unsigned short* WfH = (unsigned short*)alloc((size_t)3 * 18 * 64 * 8 * 2);
    unsigned short* WfL = (unsigned short*)alloc((size_t)3 * 18 * 64 * 8 * 2);
    (void)ws_size; (void)in_sizes; (void)n_in; (void)out_size;

    const int* srcp = ei;
    const int* dstp = ei + N_EDGES;

    init_counts<<<N_NODES / 256, 256, 0, stream>>>(cursor);
    count_edges<<<N_EDGES / 256, 256, 0, stream>>>(dstp, cursor);
    scan_kernel<<<1, 1024, 0, stream>>>(cursor, offsets);
    place_self<<<N_NODES / 256, 256, 0, stream>>>(offsets, cursor, csr_src);
    scatter_edges<<<N_EDGES / 256, 256, 0, stream>>>(srcp, dstp, cursor, csr_src);

    const float* in = x;
    for (int l = 0; l < 3; ++l) {
        const int K = (l == 0) ? IN_DIM_ : HID_;
        wsplit_frag<<<96, 256, 0, stream>>>(W[l], K, WfH, WfL);
        waug<<<96, 32, 0, stream>>>(W[l], asrc[l], adst[l], K, WfH, WfL);
        if (l == 0)
            gemm_mfma<3, IN_DIM_><<<N_NODES / 64, 256, 0, stream>>>(in, WfH, WfL, h, als, ald);
        else
            gemm_mfma<2, HID_><<<N_NODES / 64, 256, 0, stream>>>(in, WfH, WfL, h, als, ald);
        float* ho = (l & 1) ? hbuf1 : hbuf0;
        aggregate<<<N_NODES / 4, 256, 0, stream>>>(offsets, csr_src, h, als, ald, bias[l], ho);
        pool_kernel<<<NG / 4, 256, 0, stream>>>(ho, pooled, l);
        in = ho;
    }
    final_kernel<<<NG / 4, 256, 0, stream>>>(pooled, pw, pb, out);
}